// Round 1
// baseline (365.953 us; speedup 1.0000x reference)
//
#include <hip/hip_runtime.h>
#include <hip/hip_bf16.h>

#define BB 2
#define HH 16
#define SS 2048
#define DD 128

constexpr int BM = 64;   // q rows per block
constexpr int BN = 64;   // kv cols per tile
constexpr int NW = 4;    // waves per block
constexpr int QSTR = DD + 8;   // 136, row stride (elems), %8==0 keeps 16B alignment
constexpr int KSTR = DD + 8;
constexpr int VSTR = BN + 8;   // 72
constexpr int PSTR = BN + 8;

typedef __bf16 bf16_t;
typedef __attribute__((ext_vector_type(8))) __bf16 bf16x8;
typedef __attribute__((ext_vector_type(4))) __bf16 bf16x4;
typedef __attribute__((ext_vector_type(4))) float floatx4;

__global__ __launch_bounds__(256, 2)
void flexattn_fwd(const float* __restrict__ qp, const float* __restrict__ kp,
                  const float* __restrict__ vp, float* __restrict__ op)
{
    __shared__ __align__(16) bf16_t Qs[BM][QSTR];          // 17408 B
    __shared__ __align__(16) bf16_t Ks[BN][KSTR];          // 17408 B
    __shared__ __align__(16) bf16_t Vt[DD][VSTR];          // 18432 B (V transposed: Vt[d][kv])
    __shared__ __align__(16) bf16_t Ps[NW][16][PSTR];      //  9216 B (wave-private P)

    const int tid  = threadIdx.x;
    const int wave = tid >> 6;
    const int lane = tid & 63;
    const int n16  = lane & 15;
    const int quad = lane >> 4;

    const int qt = blockIdx.x;
    const int bh = blockIdx.y;
    const int h  = bh & (HH - 1);
    const int q0 = qt * BM;

    const float LOG2E  = 1.4426950408889634f;
    const float sscale = 0.08838834764831845f * LOG2E;              // (1/sqrt(128))*log2e
    const float slope  = __builtin_amdgcn_exp2f(-8.0f * (float)(h + 1) / (float)HH);
    const float bscale = slope * LOG2E;

    const float* qb = qp + (size_t)bh * SS * DD;
    const float* kb = kp + (size_t)bh * SS * DD;
    const float* vb = vp + (size_t)bh * SS * DD;
    float*       ob = op + (size_t)bh * SS * DD;

    // ---- stage Q tile (fp32 -> bf16), coalesced float4 reads, b64 LDS writes
    #pragma unroll
    for (int i = 0; i < 8; ++i) {
        int idx4 = tid + i * 256;           // 2048 float4 = 64 rows x 32
        int row  = idx4 >> 5;
        int c4   = idx4 & 31;
        const float4 val = *reinterpret_cast<const float4*>(qb + (size_t)(q0 + row) * DD + c4 * 4);
        bf16x4 w;
        w[0] = (bf16_t)val.x; w[1] = (bf16_t)val.y; w[2] = (bf16_t)val.z; w[3] = (bf16_t)val.w;
        *reinterpret_cast<bf16x4*>(&Qs[row][c4 * 4]) = w;
    }
    __syncthreads();

    // A-fragments of Q are loop-invariant: hoist. A[m=lane&15][k=quad*8+j (+32c)]
    bf16x8 qf[4];
    #pragma unroll
    for (int c = 0; c < 4; ++c)
        qf[c] = *reinterpret_cast<const bf16x8*>(&Qs[wave * 16 + n16][c * 32 + quad * 8]);

    floatx4 o[8];
    #pragma unroll
    for (int t = 0; t < 8; ++t) o[t] = (floatx4){0.f, 0.f, 0.f, 0.f};
    float m_i[4], l_i[4];
    #pragma unroll
    for (int r = 0; r < 4; ++r) { m_i[r] = -3.0e38f; l_i[r] = 0.f; }

    // kg - qg = kv0 + 16*nt - r + bias_base
    const int bias_base = n16 - (q0 + wave * 16 + quad * 4);

    for (int kt = 0; kt <= qt; ++kt) {
        const int kv0 = kt * BN;
        __syncthreads();   // protect Ks/Vt from previous iteration's readers

        // ---- stage K tile (row-major bf16)
        #pragma unroll
        for (int i = 0; i < 8; ++i) {
            int idx4 = tid + i * 256;
            int row  = idx4 >> 5;
            int c4   = idx4 & 31;
            const float4 val = *reinterpret_cast<const float4*>(kb + (size_t)(kv0 + row) * DD + c4 * 4);
            bf16x4 w;
            w[0] = (bf16_t)val.x; w[1] = (bf16_t)val.y; w[2] = (bf16_t)val.z; w[3] = (bf16_t)val.w;
            *reinterpret_cast<bf16x4*>(&Ks[row][c4 * 4]) = w;
        }
        // ---- stage V transposed: Vt[d][kv]. kv = lane -> contiguous LDS writes (2-way, free).
        // Global reads are 16B/lane at 512B stride; all 4 waves hit the same 64B lines (L1).
        #pragma unroll
        for (int i = 0; i < 8; ++i) {
            int d = wave * 4 + i * 16;      // covers all d in steps of 4
            const float4 val = *reinterpret_cast<const float4*>(vb + (size_t)(kv0 + lane) * DD + d);
            Vt[d + 0][lane] = (bf16_t)val.x;
            Vt[d + 1][lane] = (bf16_t)val.y;
            Vt[d + 2][lane] = (bf16_t)val.z;
            Vt[d + 3][lane] = (bf16_t)val.w;
        }
        __syncthreads();

        // ---- QK^T: sc[nt][r] = S[q=quad*4+r][kv=nt*16+n16]
        floatx4 sc[4];
        #pragma unroll
        for (int nt = 0; nt < 4; ++nt) {
            floatx4 acc = (floatx4){0.f, 0.f, 0.f, 0.f};
            #pragma unroll
            for (int c = 0; c < 4; ++c) {
                bf16x8 kf = *reinterpret_cast<const bf16x8*>(&Ks[nt * 16 + n16][c * 32 + quad * 8]);
                acc = __builtin_amdgcn_mfma_f32_16x16x32_bf16(qf[c], kf, acc, 0, 0, 0);
            }
            sc[nt] = acc;
        }

        // ---- scale + ALiBi + causal mask; row-max
        const bool diag = (kt == qt);
        float mt[4] = {-3.0e38f, -3.0e38f, -3.0e38f, -3.0e38f};
        #pragma unroll
        for (int nt = 0; nt < 4; ++nt) {
            #pragma unroll
            for (int r = 0; r < 4; ++r) {
                int delta = kv0 + nt * 16 + bias_base - r;   // kg - qg (<=0 in causal region)
                float sval = sc[nt][r] * sscale + bscale * (float)delta;
                if (diag && delta > 0) sval = -3.0e38f;
                sc[nt][r] = sval;
                mt[r] = fmaxf(mt[r], sval);
            }
        }
        #pragma unroll
        for (int off = 1; off < 16; off <<= 1) {
            #pragma unroll
            for (int r = 0; r < 4; ++r)
                mt[r] = fmaxf(mt[r], __shfl_xor(mt[r], off));
        }

        // ---- online softmax update
        float alpha[4], rs[4];
        #pragma unroll
        for (int r = 0; r < 4; ++r) {
            float mnew = fmaxf(m_i[r], mt[r]);
            alpha[r] = __builtin_amdgcn_exp2f(m_i[r] - mnew);   // first iter: exp2(-3e38)=0
            m_i[r] = mnew;
            rs[r] = 0.f;
        }
        #pragma unroll
        for (int nt = 0; nt < 4; ++nt) {
            #pragma unroll
            for (int r = 0; r < 4; ++r) {
                float p = __builtin_amdgcn_exp2f(sc[nt][r] - m_i[r]);
                sc[nt][r] = p;
                rs[r] += p;
            }
        }
        #pragma unroll
        for (int off = 1; off < 16; off <<= 1) {
            #pragma unroll
            for (int r = 0; r < 4; ++r)
                rs[r] += __shfl_xor(rs[r], off);
        }
        #pragma unroll
        for (int r = 0; r < 4; ++r)
            l_i[r] = l_i[r] * alpha[r] + rs[r];

        // ---- P: C-layout -> LDS -> A-layout (m120 pattern), wave-private so no barrier
        #pragma unroll
        for (int nt = 0; nt < 4; ++nt) {
            #pragma unroll
            for (int r = 0; r < 4; ++r)
                Ps[wave][quad * 4 + r][nt * 16 + n16] = (bf16_t)sc[nt][r];
        }

        // ---- rescale O accumulators
        #pragma unroll
        for (int t = 0; t < 8; ++t) {
            #pragma unroll
            for (int r = 0; r < 4; ++r)
                o[t][r] *= alpha[r];
        }

        // ---- PV: o[t] += P(16x64) * V(64x16-cols of d-tile t)
        bf16x8 pf[2];
        #pragma unroll
        for (int c = 0; c < 2; ++c)
            pf[c] = *reinterpret_cast<const bf16x8*>(&Ps[wave][n16][c * 32 + quad * 8]);
        #pragma unroll
        for (int t = 0; t < 8; ++t) {
            floatx4 acc = o[t];
            #pragma unroll
            for (int c = 0; c < 2; ++c) {
                bf16x8 vf = *reinterpret_cast<const bf16x8*>(&Vt[t * 16 + n16][c * 32 + quad * 8]);
                acc = __builtin_amdgcn_mfma_f32_16x16x32_bf16(pf[c], vf, acc, 0, 0, 0);
            }
            o[t] = acc;
        }
    }

    // ---- epilogue: O /= l, write fp32
    #pragma unroll
    for (int r = 0; r < 4; ++r) {
        float inv = 1.0f / l_i[r];
        int row = q0 + wave * 16 + quad * 4 + r;
        #pragma unroll
        for (int t = 0; t < 8; ++t)
            ob[(size_t)row * DD + t * 16 + n16] = o[t][r] * inv;
    }
}

extern "C" void kernel_launch(void* const* d_in, const int* in_sizes, int n_in,
                              void* d_out, int out_size, void* d_ws, size_t ws_size,
                              hipStream_t stream) {
    const float* q = (const float*)d_in[0];
    const float* k = (const float*)d_in[1];
    const float* v = (const float*)d_in[2];
    float* out = (float*)d_out;
    dim3 grid(SS / BM, BB * HH);
    flexattn_fwd<<<grid, 256, 0, stream>>>(q, k, v, out);
}

// Round 2
// 308.387 us; speedup vs baseline: 1.1867x; 1.1867x over previous
//
#include <hip/hip_runtime.h>
#include <hip/hip_bf16.h>

#define BB 2
#define HH 16
#define SS 2048
#define DD 128

constexpr int BM = 64;   // q rows per block
constexpr int BN = 64;   // kv cols per tile
constexpr int NW = 4;    // waves per block
constexpr int QSTR = DD + 8;   // 136
constexpr int KSTR = DD + 8;   // 136
constexpr int VSTR = BN + 8;   // 72
constexpr int PSTR = BN + 8;   // 72
constexpr size_t SD = (size_t)SS * DD;                    // 262144
constexpr size_t KV_ELEMS = (size_t)BB * HH * SS * DD;    // 8388608

typedef __bf16 bf16_t;
typedef __attribute__((ext_vector_type(8))) __bf16 bf16x8;
typedef __attribute__((ext_vector_type(4))) __bf16 bf16x4;
typedef __attribute__((ext_vector_type(4))) float floatx4;

// ---------------- pre-pass 1: K fp32 -> bf16 (elementwise) ----------------
__global__ __launch_bounds__(256)
void cvt_bf16(const float* __restrict__ in, bf16_t* __restrict__ out) {
    size_t idx = (size_t)blockIdx.x * 256 + threadIdx.x;   // float4 index
    float4 v = reinterpret_cast<const float4*>(in)[idx];
    bf16x4 w;
    w[0] = (bf16_t)v.x; w[1] = (bf16_t)v.y; w[2] = (bf16_t)v.z; w[3] = (bf16_t)v.w;
    reinterpret_cast<bf16x4*>(out)[idx] = w;
}

// ------------- pre-pass 2: V fp32 [bh][kv][d] -> bf16 Vt [bh][d][kv] -------------
__global__ __launch_bounds__(256)
void transpose_v_bf16(const float* __restrict__ vp, bf16_t* __restrict__ vt) {
    __shared__ __align__(16) bf16_t T[DD][VSTR];
    const int tid = threadIdx.x;
    const int kv0 = blockIdx.x * BN;
    const size_t bh = blockIdx.y;
    const float* vb = vp + bh * SD;
    #pragma unroll
    for (int i = 0; i < 8; ++i) {
        int idx4 = tid + i * 256;          // 2048 float4 = 64 kv-rows x 32
        int r  = idx4 >> 5;
        int c4 = idx4 & 31;
        float4 val = *reinterpret_cast<const float4*>(vb + (size_t)(kv0 + r) * DD + c4 * 4);
        T[c4 * 4 + 0][r] = (bf16_t)val.x;
        T[c4 * 4 + 1][r] = (bf16_t)val.y;
        T[c4 * 4 + 2][r] = (bf16_t)val.z;
        T[c4 * 4 + 3][r] = (bf16_t)val.w;
    }
    __syncthreads();
    #pragma unroll
    for (int i = 0; i < 4; ++i) {
        int idx = tid + i * 256;           // 1024 chunks = 128 d-rows x 8
        int d  = idx >> 3;
        int s8 = idx & 7;
        bf16x8 w = *reinterpret_cast<const bf16x8*>(&T[d][s8 * 8]);
        *reinterpret_cast<bf16x8*>(vt + (bh * DD + d) * SS + kv0 + s8 * 8) = w;
    }
}

// ---------------- main attention kernel (bf16 staged K / Vt) ----------------
__global__ __launch_bounds__(256, 3)
void flexattn_fwd_bf16(const float* __restrict__ qp, const bf16_t* __restrict__ kbf,
                       const bf16_t* __restrict__ vtbf, float* __restrict__ op)
{
    __shared__ __align__(16) bf16_t Ks[BN][KSTR];          // 17408 B
    __shared__ __align__(16) bf16_t Vt[DD][VSTR];          // 18432 B
    __shared__ __align__(16) bf16_t QPu[BM * QSTR];        // 17408 B: Q tile, reused as P
    bf16_t (*Qs)[QSTR]     = reinterpret_cast<bf16_t(*)[QSTR]>(&QPu[0]);
    bf16_t (*Ps)[16][PSTR] = reinterpret_cast<bf16_t(*)[16][PSTR]>(&QPu[0]);

    const int tid  = threadIdx.x;
    const int wave = tid >> 6;
    const int lane = tid & 63;
    const int n16  = lane & 15;
    const int quad = lane >> 4;

    const int qt = gridDim.x - 1 - blockIdx.x;   // heavy blocks dispatch first
    const int bh = blockIdx.y;
    const int h  = bh & (HH - 1);
    const int q0 = qt * BM;

    const float LOG2E  = 1.4426950408889634f;
    const float sscale = 0.08838834764831845f * LOG2E;
    const float slope  = __builtin_amdgcn_exp2f(-8.0f * (float)(h + 1) / (float)HH);
    const float bscale = slope * LOG2E;

    const float*  qb = qp   + (size_t)bh * SD;
    const bf16_t* kb = kbf  + (size_t)bh * SD;
    const bf16_t* vt = vtbf + (size_t)bh * DD * SS;
    float*        ob = op   + (size_t)bh * SD;

    // ---- stage Q tile (fp32 -> bf16)
    #pragma unroll
    for (int i = 0; i < 8; ++i) {
        int idx4 = tid + i * 256;
        int row  = idx4 >> 5;
        int c4   = idx4 & 31;
        const float4 val = *reinterpret_cast<const float4*>(qb + (size_t)(q0 + row) * DD + c4 * 4);
        bf16x4 w;
        w[0] = (bf16_t)val.x; w[1] = (bf16_t)val.y; w[2] = (bf16_t)val.z; w[3] = (bf16_t)val.w;
        *reinterpret_cast<bf16x4*>(&Qs[row][c4 * 4]) = w;
    }
    __syncthreads();

    bf16x8 qf[4];
    #pragma unroll
    for (int c = 0; c < 4; ++c)
        qf[c] = *reinterpret_cast<const bf16x8*>(&Qs[wave * 16 + n16][c * 32 + quad * 8]);

    floatx4 o[8];
    #pragma unroll
    for (int t = 0; t < 8; ++t) o[t] = (floatx4){0.f, 0.f, 0.f, 0.f};
    float m_i[4], l_i[4];
    #pragma unroll
    for (int r = 0; r < 4; ++r) { m_i[r] = -3.0e38f; l_i[r] = 0.f; }

    const int bias_base = n16 - (q0 + wave * 16 + quad * 4);
    const int pkey = (n16 >> 2) & 3;   // P-swizzle key for reads

    // ---- register prefetch pipeline
    bf16x8 kreg[4], vreg[4];
    auto issue = [&](int kt) {
        const int kv0 = kt * BN;
        #pragma unroll
        for (int i = 0; i < 4; ++i) {
            int idx = tid + i * 256;
            kreg[i] = *reinterpret_cast<const bf16x8*>(kb + (size_t)(kv0 + (idx >> 4)) * DD + (idx & 15) * 8);
            vreg[i] = *reinterpret_cast<const bf16x8*>(vt + (size_t)(idx >> 3) * SS + kv0 + (idx & 7) * 8);
        }
    };
    issue(0);

    for (int kt = 0; kt <= qt; ++kt) {
        const int kv0 = kt * BN;
        __syncthreads();   // previous iteration's LDS readers done
        #pragma unroll
        for (int i = 0; i < 4; ++i) {
            int idx = tid + i * 256;
            *reinterpret_cast<bf16x8*>(&Ks[idx >> 4][(idx & 15) * 8]) = kreg[i];
            *reinterpret_cast<bf16x8*>(&Vt[idx >> 3][(idx & 7) * 8]) = vreg[i];
        }
        __syncthreads();
        if (kt < qt) issue(kt + 1);   // lands during compute below

        // ---- QK^T
        floatx4 sc[4];
        #pragma unroll
        for (int nt = 0; nt < 4; ++nt) {
            floatx4 acc = (floatx4){0.f, 0.f, 0.f, 0.f};
            #pragma unroll
            for (int c = 0; c < 4; ++c) {
                bf16x8 kf = *reinterpret_cast<const bf16x8*>(&Ks[nt * 16 + n16][c * 32 + quad * 8]);
                acc = __builtin_amdgcn_mfma_f32_16x16x32_bf16(qf[c], kf, acc, 0, 0, 0);
            }
            sc[nt] = acc;
        }

        // ---- scale + ALiBi + causal mask; row-max
        const bool diag = (kt == qt);
        float mt[4] = {-3.0e38f, -3.0e38f, -3.0e38f, -3.0e38f};
        #pragma unroll
        for (int nt = 0; nt < 4; ++nt) {
            #pragma unroll
            for (int r = 0; r < 4; ++r) {
                int delta = kv0 + nt * 16 + bias_base - r;
                float sval = sc[nt][r] * sscale + bscale * (float)delta;
                if (diag && delta > 0) sval = -3.0e38f;
                sc[nt][r] = sval;
                mt[r] = fmaxf(mt[r], sval);
            }
        }
        #pragma unroll
        for (int off = 1; off < 16; off <<= 1) {
            #pragma unroll
            for (int r = 0; r < 4; ++r)
                mt[r] = fmaxf(mt[r], __shfl_xor(mt[r], off));
        }

        // ---- online softmax update
        float alpha[4], rs[4];
        #pragma unroll
        for (int r = 0; r < 4; ++r) {
            float mnew = fmaxf(m_i[r], mt[r]);
            alpha[r] = __builtin_amdgcn_exp2f(m_i[r] - mnew);
            m_i[r] = mnew;
            rs[r] = 0.f;
        }
        #pragma unroll
        for (int nt = 0; nt < 4; ++nt) {
            #pragma unroll
            for (int r = 0; r < 4; ++r) {
                float p = __builtin_amdgcn_exp2f(sc[nt][r] - m_i[r]);
                sc[nt][r] = p;
                rs[r] += p;
            }
        }
        #pragma unroll
        for (int off = 1; off < 16; off <<= 1) {
            #pragma unroll
            for (int r = 0; r < 4; ++r)
                rs[r] += __shfl_xor(rs[r], off);
        }
        #pragma unroll
        for (int r = 0; r < 4; ++r)
            l_i[r] = l_i[r] * alpha[r] + rs[r];

        // ---- P: C-layout -> LDS (XOR-swizzled by row-quad to kill bank conflicts)
        #pragma unroll
        for (int nt = 0; nt < 4; ++nt) {
            #pragma unroll
            for (int r = 0; r < 4; ++r)
                Ps[wave][quad * 4 + r][(nt * 16 + n16) ^ (quad * 8)] = (bf16_t)sc[nt][r];
        }

        // ---- rescale O
        #pragma unroll
        for (int t = 0; t < 8; ++t) {
            #pragma unroll
            for (int r = 0; r < 4; ++r)
                o[t][r] *= alpha[r];
        }

        // ---- PV
        bf16x8 pf[2];
        #pragma unroll
        for (int c = 0; c < 2; ++c)
            pf[c] = *reinterpret_cast<const bf16x8*>(&Ps[wave][n16][c * 32 + ((quad ^ pkey) * 8)]);
        #pragma unroll
        for (int t = 0; t < 8; ++t) {
            floatx4 acc = o[t];
            #pragma unroll
            for (int c = 0; c < 2; ++c) {
                bf16x8 vf = *reinterpret_cast<const bf16x8*>(&Vt[t * 16 + n16][c * 32 + quad * 8]);
                acc = __builtin_amdgcn_mfma_f32_16x16x32_bf16(pf[c], vf, acc, 0, 0, 0);
            }
            o[t] = acc;
        }
    }

    // ---- epilogue
    #pragma unroll
    for (int r = 0; r < 4; ++r) {
        float inv = 1.0f / l_i[r];
        int row = q0 + wave * 16 + quad * 4 + r;
        #pragma unroll
        for (int t = 0; t < 8; ++t)
            ob[(size_t)row * DD + t * 16 + n16] = o[t][r] * inv;
    }
}

// ---------------- fallback (round-1 kernel, fp32 in-kernel staging) ----------------
__global__ __launch_bounds__(256, 2)
void flexattn_fwd_f32(const float* __restrict__ qp, const float* __restrict__ kp,
                      const float* __restrict__ vp, float* __restrict__ op)
{
    __shared__ __align__(16) bf16_t Qs[BM][QSTR];
    __shared__ __align__(16) bf16_t Ks[BN][KSTR];
    __shared__ __align__(16) bf16_t Vt[DD][VSTR];
    __shared__ __align__(16) bf16_t Ps[NW][16][PSTR];

    const int tid  = threadIdx.x;
    const int wave = tid >> 6;
    const int lane = tid & 63;
    const int n16  = lane & 15;
    const int quad = lane >> 4;

    const int qt = blockIdx.x;
    const int bh = blockIdx.y;
    const int h  = bh & (HH - 1);
    const int q0 = qt * BM;

    const float LOG2E  = 1.4426950408889634f;
    const float sscale = 0.08838834764831845f * LOG2E;
    const float slope  = __builtin_amdgcn_exp2f(-8.0f * (float)(h + 1) / (float)HH);
    const float bscale = slope * LOG2E;

    const float* qb = qp + (size_t)bh * SD;
    const float* kb = kp + (size_t)bh * SD;
    const float* vb = vp + (size_t)bh * SD;
    float*       ob = op + (size_t)bh * SD;

    #pragma unroll
    for (int i = 0; i < 8; ++i) {
        int idx4 = tid + i * 256;
        int row  = idx4 >> 5;
        int c4   = idx4 & 31;
        const float4 val = *reinterpret_cast<const float4*>(qb + (size_t)(q0 + row) * DD + c4 * 4);
        bf16x4 w;
        w[0] = (bf16_t)val.x; w[1] = (bf16_t)val.y; w[2] = (bf16_t)val.z; w[3] = (bf16_t)val.w;
        *reinterpret_cast<bf16x4*>(&Qs[row][c4 * 4]) = w;
    }
    __syncthreads();

    bf16x8 qf[4];
    #pragma unroll
    for (int c = 0; c < 4; ++c)
        qf[c] = *reinterpret_cast<const bf16x8*>(&Qs[wave * 16 + n16][c * 32 + quad * 8]);

    floatx4 o[8];
    #pragma unroll
    for (int t = 0; t < 8; ++t) o[t] = (floatx4){0.f, 0.f, 0.f, 0.f};
    float m_i[4], l_i[4];
    #pragma unroll
    for (int r = 0; r < 4; ++r) { m_i[r] = -3.0e38f; l_i[r] = 0.f; }

    const int bias_base = n16 - (q0 + wave * 16 + quad * 4);

    for (int kt = 0; kt <= qt; ++kt) {
        const int kv0 = kt * BN;
        __syncthreads();
        #pragma unroll
        for (int i = 0; i < 8; ++i) {
            int idx4 = tid + i * 256;
            int row  = idx4 >> 5;
            int c4   = idx4 & 31;
            const float4 val = *reinterpret_cast<const float4*>(kb + (size_t)(kv0 + row) * DD + c4 * 4);
            bf16x4 w;
            w[0] = (bf16_t)val.x; w[1] = (bf16_t)val.y; w[2] = (bf16_t)val.z; w[3] = (bf16_t)val.w;
            *reinterpret_cast<bf16x4*>(&Ks[row][c4 * 4]) = w;
        }
        #pragma unroll
        for (int i = 0; i < 8; ++i) {
            int d = wave * 4 + i * 16;
            const float4 val = *reinterpret_cast<const float4*>(vb + (size_t)(kv0 + lane) * DD + d);
            Vt[d + 0][lane] = (bf16_t)val.x;
            Vt[d + 1][lane] = (bf16_t)val.y;
            Vt[d + 2][lane] = (bf16_t)val.z;
            Vt[d + 3][lane] = (bf16_t)val.w;
        }
        __syncthreads();

        floatx4 sc[4];
        #pragma unroll
        for (int nt = 0; nt < 4; ++nt) {
            floatx4 acc = (floatx4){0.f, 0.f, 0.f, 0.f};
            #pragma unroll
            for (int c = 0; c < 4; ++c) {
                bf16x8 kf = *reinterpret_cast<const bf16x8*>(&Ks[nt * 16 + n16][c * 32 + quad * 8]);
                acc = __builtin_amdgcn_mfma_f32_16x16x32_bf16(qf[c], kf, acc, 0, 0, 0);
            }
            sc[nt] = acc;
        }

        const bool diag = (kt == qt);
        float mt[4] = {-3.0e38f, -3.0e38f, -3.0e38f, -3.0e38f};
        #pragma unroll
        for (int nt = 0; nt < 4; ++nt) {
            #pragma unroll
            for (int r = 0; r < 4; ++r) {
                int delta = kv0 + nt * 16 + bias_base - r;
                float sval = sc[nt][r] * sscale + bscale * (float)delta;
                if (diag && delta > 0) sval = -3.0e38f;
                sc[nt][r] = sval;
                mt[r] = fmaxf(mt[r], sval);
            }
        }
        #pragma unroll
        for (int off = 1; off < 16; off <<= 1) {
            #pragma unroll
            for (int r = 0; r < 4; ++r)
                mt[r] = fmaxf(mt[r], __shfl_xor(mt[r], off));
        }

        float alpha[4], rs[4];
        #pragma unroll
        for (int r = 0; r < 4; ++r) {
            float mnew = fmaxf(m_i[r], mt[r]);
            alpha[r] = __builtin_amdgcn_exp2f(m_i[r] - mnew);
            m_i[r] = mnew;
            rs[r] = 0.f;
        }
        #pragma unroll
        for (int nt = 0; nt < 4; ++nt) {
            #pragma unroll
            for (int r = 0; r < 4; ++r) {
                float p = __builtin_amdgcn_exp2f(sc[nt][r] - m_i[r]);
                sc[nt][r] = p;
                rs[r] += p;
            }
        }
        #pragma unroll
        for (int off = 1; off < 16; off <<= 1) {
            #pragma unroll
            for (int r = 0; r < 4; ++r)
                rs[r] += __shfl_xor(rs[r], off);
        }
        #pragma unroll
        for (int r = 0; r < 4; ++r)
            l_i[r] = l_i[r] * alpha[r] + rs[r];

        #pragma unroll
        for (int nt = 0; nt < 4; ++nt) {
            #pragma unroll
            for (int r = 0; r < 4; ++r)
                Ps[wave][quad * 4 + r][nt * 16 + n16] = (bf16_t)sc[nt][r];
        }

        #pragma unroll
        for (int t = 0; t < 8; ++t) {
            #pragma unroll
            for (int r = 0; r < 4; ++r)
                o[t][r] *= alpha[r];
        }

        bf16x8 pf[2];
        #pragma unroll
        for (int c = 0; c < 2; ++c)
            pf[c] = *reinterpret_cast<const bf16x8*>(&Ps[wave][n16][c * 32 + quad * 8]);
        #pragma unroll
        for (int t = 0; t < 8; ++t) {
            floatx4 acc = o[t];
            #pragma unroll
            for (int c = 0; c < 2; ++c) {
                bf16x8 vf = *reinterpret_cast<const bf16x8*>(&Vt[t * 16 + n16][c * 32 + quad * 8]);
                acc = __builtin_amdgcn_mfma_f32_16x16x32_bf16(pf[c], vf, acc, 0, 0, 0);
            }
            o[t] = acc;
        }
    }

    #pragma unroll
    for (int r = 0; r < 4; ++r) {
        float inv = 1.0f / l_i[r];
        int row = q0 + wave * 16 + quad * 4 + r;
        #pragma unroll
        for (int t = 0; t < 8; ++t)
            ob[(size_t)row * DD + t * 16 + n16] = o[t][r] * inv;
    }
}

extern "C" void kernel_launch(void* const* d_in, const int* in_sizes, int n_in,
                              void* d_out, int out_size, void* d_ws, size_t ws_size,
                              hipStream_t stream) {
    const float* q = (const float*)d_in[0];
    const float* k = (const float*)d_in[1];
    const float* v = (const float*)d_in[2];
    float* out = (float*)d_out;

    const size_t need = KV_ELEMS * sizeof(bf16_t) * 2;   // 33.6 MB
    if (ws_size >= need) {
        bf16_t* kbf  = (bf16_t*)d_ws;
        bf16_t* vtbf = kbf + KV_ELEMS;
        cvt_bf16<<<(int)(KV_ELEMS / 4 / 256), 256, 0, stream>>>(k, kbf);
        transpose_v_bf16<<<dim3(SS / BN, BB * HH), 256, 0, stream>>>(v, vtbf);
        flexattn_fwd_bf16<<<dim3(SS / BM, BB * HH), 256, 0, stream>>>(q, kbf, vtbf, out);
    } else {
        flexattn_fwd_f32<<<dim3(SS / BM, BB * HH), 256, 0, stream>>>(q, k, v, out);
    }
}

// Round 3
// 269.079 us; speedup vs baseline: 1.3600x; 1.1461x over previous
//
#include <hip/hip_runtime.h>
#include <hip/hip_bf16.h>

#define BB 2
#define HH 16
#define SS 2048
#define DD 128

constexpr int BM = 64;   // q rows per block
constexpr int BN = 64;   // kv cols per tile
constexpr int NW = 4;    // waves per block
constexpr int QSTR = DD + 8;   // 136
constexpr int KSTR = DD + 8;   // 136
constexpr int VSTR = BN + 8;   // 72
constexpr int PSTR = BN + 8;   // 72
constexpr size_t SD = (size_t)SS * DD;                    // 262144
constexpr size_t KV_ELEMS = (size_t)BB * HH * SS * DD;    // 8388608

typedef __bf16 bf16_t;
typedef __attribute__((ext_vector_type(8))) __bf16 bf16x8;
typedef __attribute__((ext_vector_type(4))) __bf16 bf16x4;
typedef __attribute__((ext_vector_type(4))) float floatx4;

// ---------------- fused pre-pass: K fp32->bf16 copy, V fp32->bf16 transpose ----------------
// V transpose goes through L1 (lane=kv strided reads, d-major coalesced writes): no LDS at all.
__global__ __launch_bounds__(256)
void prep_kv(const float* __restrict__ kp, const float* __restrict__ vp,
             bf16_t* __restrict__ kbf, bf16_t* __restrict__ vtbf)
{
    const int tid  = threadIdx.x;
    const int lane = tid & 63;
    const int w    = tid >> 6;
    const int kv0  = blockIdx.x * BN;
    const size_t bh = blockIdx.y;

    const float* kb = kp + bh * SD;
    const float* vb = vp + bh * SD;
    bf16_t* ko = kbf  + bh * SD;
    bf16_t* vo = vtbf + bh * (size_t)DD * SS;

    // K: straight row-major convert, fully coalesced both sides
    #pragma unroll
    for (int i = 0; i < 8; ++i) {
        int idx4 = tid + i * 256;           // 2048 float4 = 64 rows x 32
        int row  = idx4 >> 5;
        int c4   = idx4 & 31;
        float4 val = *reinterpret_cast<const float4*>(kb + (size_t)(kv0 + row) * DD + c4 * 4);
        bf16x4 o;
        o[0] = (bf16_t)val.x; o[1] = (bf16_t)val.y; o[2] = (bf16_t)val.z; o[3] = (bf16_t)val.w;
        *reinterpret_cast<bf16x4*>(ko + (size_t)(kv0 + row) * DD + c4 * 4) = o;
    }

    // V: lane = kv (strided 512B reads, L1 catches re-use), d-major contiguous 128B writes
    const int kv = kv0 + lane;
    #pragma unroll
    for (int i = 0; i < 8; ++i) {
        int d = w * 32 + i * 4;
        float4 val = *reinterpret_cast<const float4*>(vb + (size_t)kv * DD + d);
        vo[(size_t)(d + 0) * SS + kv] = (bf16_t)val.x;
        vo[(size_t)(d + 1) * SS + kv] = (bf16_t)val.y;
        vo[(size_t)(d + 2) * SS + kv] = (bf16_t)val.z;
        vo[(size_t)(d + 3) * SS + kv] = (bf16_t)val.w;
    }
}

// ---------------- main attention kernel: transposed S (per-lane softmax rows) ----------------
__global__ __launch_bounds__(256, 3)
void flexattn_fwd_bf16(const float* __restrict__ qp, const bf16_t* __restrict__ kbf,
                       const bf16_t* __restrict__ vtbf, float* __restrict__ op)
{
    __shared__ __align__(16) bf16_t Ks[BN][KSTR];          // 17408 B
    __shared__ __align__(16) bf16_t Vt[DD][VSTR];          // 18432 B
    __shared__ __align__(16) bf16_t QPu[BM * QSTR];        // 17408 B: Q tile, reused as P
    bf16_t (*Qs)[QSTR]     = reinterpret_cast<bf16_t(*)[QSTR]>(&QPu[0]);
    bf16_t (*Ps)[16][PSTR] = reinterpret_cast<bf16_t(*)[16][PSTR]>(&QPu[0]);

    const int tid  = threadIdx.x;
    const int wave = tid >> 6;
    const int lane = tid & 63;
    const int n16  = lane & 15;
    const int quad = lane >> 4;

    const int qt = gridDim.x - 1 - blockIdx.x;   // heavy blocks dispatch first
    const int bh = blockIdx.y;
    const int h  = bh & (HH - 1);
    const int q0 = qt * BM;

    const float LOG2E  = 1.4426950408889634f;
    const float sscale = 0.08838834764831845f * LOG2E;
    const float slope  = __builtin_amdgcn_exp2f(-8.0f * (float)(h + 1) / (float)HH);
    const float bscale = slope * LOG2E;

    const float*  qb = qp   + (size_t)bh * SD;
    const bf16_t* kb = kbf  + (size_t)bh * SD;
    const bf16_t* vt = vtbf + (size_t)bh * (size_t)DD * SS;
    float*        ob = op   + (size_t)bh * SD;

    // ---- stage Q tile (fp32 -> bf16) into QPu
    #pragma unroll
    for (int i = 0; i < 8; ++i) {
        int idx4 = tid + i * 256;
        int row  = idx4 >> 5;
        int c4   = idx4 & 31;
        const float4 val = *reinterpret_cast<const float4*>(qb + (size_t)(q0 + row) * DD + c4 * 4);
        bf16x4 w;
        w[0] = (bf16_t)val.x; w[1] = (bf16_t)val.y; w[2] = (bf16_t)val.z; w[3] = (bf16_t)val.w;
        *reinterpret_cast<bf16x4*>(&Qs[row][c4 * 4]) = w;
    }
    __syncthreads();

    // Q fragments (serve as MFMA B-operand: B[k=d][n=q], n=lane&15)
    bf16x8 qf[4];
    #pragma unroll
    for (int c = 0; c < 4; ++c)
        qf[c] = *reinterpret_cast<const bf16x8*>(&Qs[wave * 16 + n16][c * 32 + quad * 8]);

    // O^T accumulators: o[t] -> O^T[d = t*16 + quad*4 + r][q = wave*16 + n16]
    floatx4 o[8];
    #pragma unroll
    for (int t = 0; t < 8; ++t) o[t] = (floatx4){0.f, 0.f, 0.f, 0.f};
    float m_i = -3.0e38f, l_i = 0.f;   // per-lane scalars (lane owns q-row wave*16+n16)

    // delta = kv_g - q_g = kv0 + nt*16 + r + bias_base
    const int bias_base = quad * 4 - (q0 + wave * 16 + n16);

    // ---- register prefetch pipeline
    bf16x8 kreg[4], vreg[4];
    auto issue = [&](int kt) {
        const int kv0 = kt * BN;
        #pragma unroll
        for (int i = 0; i < 4; ++i) {
            int idx = tid + i * 256;
            kreg[i] = *reinterpret_cast<const bf16x8*>(kb + (size_t)(kv0 + (idx >> 4)) * DD + (idx & 15) * 8);
            vreg[i] = *reinterpret_cast<const bf16x8*>(vt + (size_t)(idx >> 3) * SS + kv0 + (idx & 7) * 8);
        }
    };
    issue(0);

    for (int kt = 0; kt <= qt; ++kt) {
        const int kv0 = kt * BN;
        __syncthreads();
        #pragma unroll
        for (int i = 0; i < 4; ++i) {
            int idx = tid + i * 256;
            *reinterpret_cast<bf16x8*>(&Ks[idx >> 4][(idx & 15) * 8]) = kreg[i];
            *reinterpret_cast<bf16x8*>(&Vt[idx >> 3][(idx & 7) * 8]) = vreg[i];
        }
        __syncthreads();
        if (kt < qt) issue(kt + 1);

        // ---- S^T = K * Q^T : sc[nt][r] = S[q = wave*16+n16][kv = kv0 + nt*16 + quad*4 + r]
        floatx4 sc[4];
        #pragma unroll
        for (int nt = 0; nt < 4; ++nt) {
            floatx4 acc = (floatx4){0.f, 0.f, 0.f, 0.f};
            #pragma unroll
            for (int c = 0; c < 4; ++c) {
                bf16x8 kf = *reinterpret_cast<const bf16x8*>(&Ks[nt * 16 + n16][c * 32 + quad * 8]);
                acc = __builtin_amdgcn_mfma_f32_16x16x32_bf16(kf, qf[c], acc, 0, 0, 0);
            }
            sc[nt] = acc;
        }

        // ---- scale + ALiBi + causal; in-lane row-max over 16 vals + 2 shuffles
        const bool diag = (kt == qt);
        float mloc = -3.0e38f;
        #pragma unroll
        for (int nt = 0; nt < 4; ++nt) {
            #pragma unroll
            for (int r = 0; r < 4; ++r) {
                int delta = kv0 + nt * 16 + r + bias_base;
                float sval = sc[nt][r] * sscale + bscale * (float)delta;
                if (diag && delta > 0) sval = -3.0e38f;
                sc[nt][r] = sval;
                mloc = fmaxf(mloc, sval);
            }
        }
        mloc = fmaxf(mloc, __shfl_xor(mloc, 16));
        mloc = fmaxf(mloc, __shfl_xor(mloc, 32));

        const float mnew  = fmaxf(m_i, mloc);
        const float alpha = __builtin_amdgcn_exp2f(m_i - mnew);
        m_i = mnew;

        float rs = 0.f;
        #pragma unroll
        for (int nt = 0; nt < 4; ++nt) {
            #pragma unroll
            for (int r = 0; r < 4; ++r) {
                float p = __builtin_amdgcn_exp2f(sc[nt][r] - mnew);
                sc[nt][r] = p;
                rs += p;
            }
        }
        rs += __shfl_xor(rs, 16);
        rs += __shfl_xor(rs, 32);
        l_i = l_i * alpha + rs;

        // ---- P^T -> LDS, permuted col s = quad*16 + nt*4 + r (lane-contiguous: 2x b128)
        bf16x8 p0, p1;
        #pragma unroll
        for (int r = 0; r < 4; ++r) {
            p0[r]     = (bf16_t)sc[0][r];
            p0[r + 4] = (bf16_t)sc[1][r];
            p1[r]     = (bf16_t)sc[2][r];
            p1[r + 4] = (bf16_t)sc[3][r];
        }
        *reinterpret_cast<bf16x8*>(&Ps[wave][n16][quad * 16])     = p0;
        *reinterpret_cast<bf16x8*>(&Ps[wave][n16][quad * 16 + 8]) = p1;

        // ---- rescale O^T by per-lane scalar alpha
        #pragma unroll
        for (int t = 0; t < 8; ++t) {
            #pragma unroll
            for (int r = 0; r < 4; ++r)
                o[t][r] *= alpha;
        }

        // ---- read P^T as B-fragment: B[k=kv=32c+quad*8+j][n=q=n16]
        // kv -> s: s = ((2*quad + j4)&3)*16 + (2c + (quad>>1))*4 + (j&3)
        bf16x8 pf[2];
        #pragma unroll
        for (int c = 0; c < 2; ++c) {
            #pragma unroll
            for (int j4 = 0; j4 < 2; ++j4) {
                int s0 = (((2 * quad + j4) & 3) * 16) + ((2 * c + (quad >> 1)) * 4);
                bf16x4 ph = *reinterpret_cast<const bf16x4*>(&Ps[wave][n16][s0]);
                pf[c][j4 * 4 + 0] = ph[0];
                pf[c][j4 * 4 + 1] = ph[1];
                pf[c][j4 * 4 + 2] = ph[2];
                pf[c][j4 * 4 + 3] = ph[3];
            }
        }

        // ---- O^T += V^T * P^T
        #pragma unroll
        for (int t = 0; t < 8; ++t) {
            floatx4 acc = o[t];
            #pragma unroll
            for (int c = 0; c < 2; ++c) {
                bf16x8 vf = *reinterpret_cast<const bf16x8*>(&Vt[t * 16 + n16][c * 32 + quad * 8]);
                acc = __builtin_amdgcn_mfma_f32_16x16x32_bf16(vf, pf[c], acc, 0, 0, 0);
            }
            o[t] = acc;
        }
    }

    // ---- epilogue: O[q][d], lane holds q = wave*16+n16, d = t*16 + quad*4 + {0..3} (float4)
    const float inv = 1.0f / l_i;
    const size_t rowoff = (size_t)(q0 + wave * 16 + n16) * DD;
    #pragma unroll
    for (int t = 0; t < 8; ++t) {
        float4 w;
        w.x = o[t][0] * inv; w.y = o[t][1] * inv;
        w.z = o[t][2] * inv; w.w = o[t][3] * inv;
        *reinterpret_cast<float4*>(ob + rowoff + t * 16 + quad * 4) = w;
    }
}

extern "C" void kernel_launch(void* const* d_in, const int* in_sizes, int n_in,
                              void* d_out, int out_size, void* d_ws, size_t ws_size,
                              hipStream_t stream) {
    const float* q = (const float*)d_in[0];
    const float* k = (const float*)d_in[1];
    const float* v = (const float*)d_in[2];
    float* out = (float*)d_out;

    bf16_t* kbf  = (bf16_t*)d_ws;
    bf16_t* vtbf = kbf + KV_ELEMS;
    prep_kv<<<dim3(SS / BN, BB * HH), 256, 0, stream>>>(k, v, kbf, vtbf);
    flexattn_fwd_bf16<<<dim3(SS / BM, BB * HH), 256, 0, stream>>>(q, kbf, vtbf, out);
}